// Round 1
// baseline (1361.465 us; speedup 1.0000x reference)
//
#include <hip/hip_runtime.h>
#include <math.h>

#define B_TOK 4096
#define D_DIM 1024
#define H_DIM 2048
#define O_DIM 1024
#define E_NUM 16
#define K_TOP 4

#define BM 128
#define BN 128
#define BK 32

typedef __attribute__((ext_vector_type(4))) float f32x4;
typedef __attribute__((ext_vector_type(8))) short bf16x8;

__device__ __forceinline__ unsigned short f2b(float f) {
  unsigned u = __builtin_bit_cast(unsigned, f);
  u = u + 0x7FFFu + ((u >> 16) & 1u);
  return (unsigned short)(u >> 16);
}
__device__ __forceinline__ float b2f(unsigned short s) {
  return __builtin_bit_cast(float, ((unsigned)s) << 16);
}

// ---------------------------------------------------------------- gating ----
__global__ __launch_bounds__(256) void gating_kernel(
    const float* __restrict__ x, const float* __restrict__ noise,
    const float* __restrict__ w_gate, const float* __restrict__ w_noise,
    int* __restrict__ counts, int* __restrict__ pair_v,
    float* __restrict__ gate_bk, float* __restrict__ gates_full,
    float* __restrict__ prob_ws)
{
  const int b = blockIdx.x;
  const int t = threadIdx.x;
  const int e = t & 15, seg = t >> 4;           // 16 segs x 64 d each
  const float* __restrict__ xr = x + (size_t)b * D_DIM;

  float pg = 0.f, pn = 0.f;
  #pragma unroll 8
  for (int j = 0; j < 64; ++j) {
    const int d = seg * 64 + j;
    const float xv = xr[d];
    pg += xv * w_gate[d * E_NUM + e];
    pn += xv * w_noise[d * E_NUM + e];
  }
  __shared__ float sg[16][16], sn[16][16];
  sg[seg][e] = pg; sn[seg][e] = pn;
  __syncthreads();

  __shared__ float s_clean[16], s_std[16], s_noisy[16];
  if (t < 32) {
    const int which = t >> 4, ee = t & 15;
    float s = 0.f;
    #pragma unroll
    for (int i = 0; i < 16; ++i) s += which ? sn[i][ee] : sg[i][ee];
    if (which == 0) s_clean[ee] = s;
    else {
      const float sp = (s > 0.f) ? (s + log1pf(expf(-s))) : log1pf(expf(s));
      s_std[ee] = sp + 0.01f;
    }
  }
  __syncthreads();
  if (t < 16) s_noisy[t] = s_clean[t] + noise[(size_t)b * E_NUM + t] * s_std[t];
  __syncthreads();

  __shared__ float s_top[5];
  __shared__ int   s_idx[4];
  __shared__ float s_gates[4];
  if (t == 0) {
    float v[16];
    #pragma unroll
    for (int i = 0; i < 16; ++i) v[i] = s_noisy[i];
    unsigned mask = 0;
    float tv[5]; int ti[5];
    #pragma unroll
    for (int k = 0; k < 5; ++k) {
      float best = -3.4e38f; int bi = 0;
      #pragma unroll
      for (int i = 0; i < 16; ++i) {
        const bool ok = !((mask >> i) & 1u) && (v[i] > best);
        best = ok ? v[i] : best;
        bi   = ok ? i    : bi;
      }
      mask |= (1u << bi);
      tv[k] = best; ti[k] = bi;
    }
    const float m = tv[0];
    float ex[4], se = 0.f;
    #pragma unroll
    for (int k = 0; k < 4; ++k) { ex[k] = expf(tv[k] - m); se += ex[k]; }
    #pragma unroll
    for (int k = 0; k < 4; ++k) s_gates[k] = ex[k] / se;
    #pragma unroll
    for (int k = 0; k < 5; ++k) s_top[k] = tv[k];
    #pragma unroll
    for (int k = 0; k < 4; ++k) s_idx[k] = ti[k];
  }
  __syncthreads();

  if (t < 16) gates_full[(size_t)b * E_NUM + t] = 0.f;
  __syncthreads();
  if (t < 4) {
    const int ee = s_idx[t];
    const float g = s_gates[t];
    gate_bk[b * K_TOP + t] = g;
    gates_full[(size_t)b * E_NUM + ee] = g;
    const int slot = atomicAdd(&counts[ee], 1);
    pair_v[ee * B_TOK + slot] = b * K_TOP + t;     // h-row index = b*4 + rank
  }
  if (t < 16) {
    const float thr_in = s_top[4], thr_out = s_top[3];
    const float thr = (s_noisy[t] > thr_in) ? thr_in : thr_out;
    const float z = (s_clean[t] - thr) / s_std[t];
    prob_ws[(size_t)b * E_NUM + t] = 0.5f * (1.f + erff(z * 0.70710678118654752f));
  }
}

// ----------------------------------------------------------------- GEMM1 ----
// h[pair_row][n] = relu( x[tok] @ W1[e] + b1[e] ),  grouped by expert.
__global__ __launch_bounds__(256) void gemm1_kernel(
    const float* __restrict__ x, const float* __restrict__ W1,
    const float* __restrict__ b1g, const int* __restrict__ counts,
    const int* __restrict__ pair_v, unsigned short* __restrict__ h)
{
  const int e = blockIdx.z;
  const int cnt = counts[e];
  const int m0 = blockIdx.x * BM;
  if (m0 >= cnt) return;
  const int n0 = blockIdx.y * BN;
  const float* __restrict__ W = W1 + (size_t)e * D_DIM * H_DIM;
  const int* __restrict__ plist = pair_v + e * B_TOK;

  __shared__ __align__(16) unsigned short As[2][BM * BK];
  __shared__ __align__(16) unsigned short Bs[2][BN * BK];
  __shared__ int hrow_s[BM];

  const int t = threadIdx.x;
  if (t < BM) {
    const int i = m0 + t;
    hrow_s[t] = (i < cnt) ? plist[i] : -1;
  }
  __syncthreads();

  // A staging: thread -> (row ar, k-half ah), 16 fp32 -> 2 swizzled b128 writes
  const int ar = t >> 1, ah = t & 1;
  const int hvA = hrow_s[ar];
  const float* __restrict__ a_src = x + (size_t)((hvA >= 0) ? (hvA >> 2) : 0) * D_DIM + ah * 16;
  const int aoff0 = ar * BK + ((((ah << 1))     ^ ((ar >> 1) & 3)) << 3);
  const int aoff1 = ar * BK + ((((ah << 1) + 1) ^ ((ar >> 1) & 3)) << 3);

  // B staging: thread -> (col bn, k-half bgh); 16 scalar fp32 loads (coalesced
  // across lanes), packed into 2 swizzled b128 writes of transposed tile [n][k]
  const int bn = t & 127, bgh = t >> 7;
  const float* __restrict__ b_src = W + (size_t)(bgh * 16) * H_DIM + (n0 + bn);
  const int boff0 = bn * BK + ((((bgh << 1))     ^ ((bn >> 1) & 3)) << 3);
  const int boff1 = bn * BK + ((((bgh << 1) + 1) ^ ((bn >> 1) & 3)) << 3);

  const int l = t & 63, wv = t >> 6;
  const int wm = wv >> 1, wn = wv & 1;
  const int gA = l >> 4;

  f32x4 acc[4][4];
  #pragma unroll
  for (int i = 0; i < 4; ++i)
    #pragma unroll
    for (int j = 0; j < 4; ++j)
      acc[i][j] = (f32x4){0.f, 0.f, 0.f, 0.f};

  { // prologue: stage k0 = 0 into buf 0
    const f32x4* ap = (const f32x4*)a_src;
    f32x4 a0 = ap[0], a1 = ap[1], a2 = ap[2], a3 = ap[3];
    float bvv[16];
    #pragma unroll
    for (int j = 0; j < 16; ++j) bvv[j] = b_src[(size_t)j * H_DIM];
    bf16x8 p0, p1;
    #pragma unroll
    for (int q = 0; q < 4; ++q) {
      p0[q] = (short)f2b(a0[q]); p0[q + 4] = (short)f2b(a1[q]);
      p1[q] = (short)f2b(a2[q]); p1[q + 4] = (short)f2b(a3[q]);
    }
    *(bf16x8*)&As[0][aoff0] = p0;
    *(bf16x8*)&As[0][aoff1] = p1;
    bf16x8 q0, q1;
    #pragma unroll
    for (int q = 0; q < 8; ++q) { q0[q] = (short)f2b(bvv[q]); q1[q] = (short)f2b(bvv[q + 8]); }
    *(bf16x8*)&Bs[0][boff0] = q0;
    *(bf16x8*)&Bs[0][boff1] = q1;
  }
  __syncthreads();

  int buf = 0;
  const int KITERS = D_DIM / BK;
  for (int kt = 0; kt < KITERS; ++kt) {
    bf16x8 af[4], bfr[4];
    #pragma unroll
    for (int i = 0; i < 4; ++i) {
      const int r = wm * 64 + i * 16 + (l & 15);
      af[i]  = *(const bf16x8*)&As[buf][r * BK + ((gA ^ ((r >> 1) & 3)) << 3)];
      const int c = wn * 64 + i * 16 + (l & 15);
      bfr[i] = *(const bf16x8*)&Bs[buf][c * BK + ((gA ^ ((c >> 1) & 3)) << 3)];
    }
    const bool more = (kt + 1 < KITERS);
    f32x4 a0, a1, a2, a3;
    float bvv[16];
    if (more) {  // issue next-tile global loads before MFMA (hide latency)
      const int k0 = (kt + 1) * BK;
      const f32x4* ap = (const f32x4*)(a_src + k0);
      a0 = ap[0]; a1 = ap[1]; a2 = ap[2]; a3 = ap[3];
      #pragma unroll
      for (int j = 0; j < 16; ++j) bvv[j] = b_src[(size_t)(k0 + j) * H_DIM];
    }
    #pragma unroll
    for (int i = 0; i < 4; ++i)
      #pragma unroll
      for (int j = 0; j < 4; ++j)
        acc[i][j] = __builtin_amdgcn_mfma_f32_16x16x32_bf16(af[i], bfr[j], acc[i][j], 0, 0, 0);
    if (more) {
      bf16x8 p0, p1;
      #pragma unroll
      for (int q = 0; q < 4; ++q) {
        p0[q] = (short)f2b(a0[q]); p0[q + 4] = (short)f2b(a1[q]);
        p1[q] = (short)f2b(a2[q]); p1[q + 4] = (short)f2b(a3[q]);
      }
      *(bf16x8*)&As[buf ^ 1][aoff0] = p0;
      *(bf16x8*)&As[buf ^ 1][aoff1] = p1;
      bf16x8 q0, q1;
      #pragma unroll
      for (int q = 0; q < 8; ++q) { q0[q] = (short)f2b(bvv[q]); q1[q] = (short)f2b(bvv[q + 8]); }
      *(bf16x8*)&Bs[buf ^ 1][boff0] = q0;
      *(bf16x8*)&Bs[buf ^ 1][boff1] = q1;
    }
    __syncthreads();
    buf ^= 1;
  }

  const float* __restrict__ bias = b1g + (size_t)e * H_DIM + n0;
  #pragma unroll
  for (int i = 0; i < 4; ++i) {
    #pragma unroll
    for (int j = 0; j < 4; ++j) {
      const int col = wn * 64 + j * 16 + (l & 15);
      const float bb = bias[col];
      #pragma unroll
      for (int q = 0; q < 4; ++q) {
        const int r = wm * 64 + i * 16 + gA * 4 + q;
        const int hr = hrow_s[r];
        if (hr >= 0) {
          float v = acc[i][j][q] + bb;
          v = v > 0.f ? v : 0.f;
          h[(size_t)hr * H_DIM + (n0 + col)] = f2b(v);
        }
      }
    }
  }
}

// ----------------------------------------------------------------- GEMM2 ----
// out[pair_row][o] = h[pair_row] @ W2[e] + b2[e]   (bf16 in, bf16 out)
__global__ __launch_bounds__(256) void gemm2_kernel(
    const unsigned short* __restrict__ h, const float* __restrict__ W2,
    const float* __restrict__ b2g, const int* __restrict__ counts,
    const int* __restrict__ pair_v, unsigned short* __restrict__ outw)
{
  const int e = blockIdx.z;
  const int cnt = counts[e];
  const int m0 = blockIdx.x * BM;
  if (m0 >= cnt) return;
  const int n0 = blockIdx.y * BN;
  const float* __restrict__ W = W2 + (size_t)e * H_DIM * O_DIM;
  const int* __restrict__ plist = pair_v + e * B_TOK;

  __shared__ __align__(16) unsigned short As[2][BM * BK];
  __shared__ __align__(16) unsigned short Bs[2][BN * BK];
  __shared__ int hrow_s[BM];

  const int t = threadIdx.x;
  if (t < BM) {
    const int i = m0 + t;
    hrow_s[t] = (i < cnt) ? plist[i] : -1;
  }
  __syncthreads();

  const int ar = t >> 1, ah = t & 1;
  const int hvA = hrow_s[ar];
  const unsigned short* __restrict__ a_src =
      h + (size_t)((hvA >= 0) ? hvA : 0) * H_DIM + ah * 16;
  const int aoff0 = ar * BK + ((((ah << 1))     ^ ((ar >> 1) & 3)) << 3);
  const int aoff1 = ar * BK + ((((ah << 1) + 1) ^ ((ar >> 1) & 3)) << 3);

  const int bn = t & 127, bgh = t >> 7;
  const float* __restrict__ b_src = W + (size_t)(bgh * 16) * O_DIM + (n0 + bn);
  const int boff0 = bn * BK + ((((bgh << 1))     ^ ((bn >> 1) & 3)) << 3);
  const int boff1 = bn * BK + ((((bgh << 1) + 1) ^ ((bn >> 1) & 3)) << 3);

  const int l = t & 63, wv = t >> 6;
  const int wm = wv >> 1, wn = wv & 1;
  const int gA = l >> 4;

  f32x4 acc[4][4];
  #pragma unroll
  for (int i = 0; i < 4; ++i)
    #pragma unroll
    for (int j = 0; j < 4; ++j)
      acc[i][j] = (f32x4){0.f, 0.f, 0.f, 0.f};

  {
    bf16x8 p0 = *(const bf16x8*)(a_src);
    bf16x8 p1 = *(const bf16x8*)(a_src + 8);
    float bvv[16];
    #pragma unroll
    for (int j = 0; j < 16; ++j) bvv[j] = b_src[(size_t)j * O_DIM];
    *(bf16x8*)&As[0][aoff0] = p0;
    *(bf16x8*)&As[0][aoff1] = p1;
    bf16x8 q0, q1;
    #pragma unroll
    for (int q = 0; q < 8; ++q) { q0[q] = (short)f2b(bvv[q]); q1[q] = (short)f2b(bvv[q + 8]); }
    *(bf16x8*)&Bs[0][boff0] = q0;
    *(bf16x8*)&Bs[0][boff1] = q1;
  }
  __syncthreads();

  int buf = 0;
  const int KITERS = H_DIM / BK;
  for (int kt = 0; kt < KITERS; ++kt) {
    bf16x8 af[4], bfr[4];
    #pragma unroll
    for (int i = 0; i < 4; ++i) {
      const int r = wm * 64 + i * 16 + (l & 15);
      af[i]  = *(const bf16x8*)&As[buf][r * BK + ((gA ^ ((r >> 1) & 3)) << 3)];
      const int c = wn * 64 + i * 16 + (l & 15);
      bfr[i] = *(const bf16x8*)&Bs[buf][c * BK + ((gA ^ ((c >> 1) & 3)) << 3)];
    }
    const bool more = (kt + 1 < KITERS);
    bf16x8 p0, p1;
    float bvv[16];
    if (more) {
      const int k0 = (kt + 1) * BK;
      p0 = *(const bf16x8*)(a_src + k0);
      p1 = *(const bf16x8*)(a_src + k0 + 8);
      #pragma unroll
      for (int j = 0; j < 16; ++j) bvv[j] = b_src[(size_t)(k0 + j) * O_DIM];
    }
    #pragma unroll
    for (int i = 0; i < 4; ++i)
      #pragma unroll
      for (int j = 0; j < 4; ++j)
        acc[i][j] = __builtin_amdgcn_mfma_f32_16x16x32_bf16(af[i], bfr[j], acc[i][j], 0, 0, 0);
    if (more) {
      *(bf16x8*)&As[buf ^ 1][aoff0] = p0;
      *(bf16x8*)&As[buf ^ 1][aoff1] = p1;
      bf16x8 q0, q1;
      #pragma unroll
      for (int q = 0; q < 8; ++q) { q0[q] = (short)f2b(bvv[q]); q1[q] = (short)f2b(bvv[q + 8]); }
      *(bf16x8*)&Bs[buf ^ 1][boff0] = q0;
      *(bf16x8*)&Bs[buf ^ 1][boff1] = q1;
    }
    __syncthreads();
    buf ^= 1;
  }

  const float* __restrict__ bias = b2g + (size_t)e * O_DIM + n0;
  #pragma unroll
  for (int i = 0; i < 4; ++i) {
    #pragma unroll
    for (int j = 0; j < 4; ++j) {
      const int col = wn * 64 + j * 16 + (l & 15);
      const float bb = bias[col];
      #pragma unroll
      for (int q = 0; q < 4; ++q) {
        const int r = wm * 64 + i * 16 + gA * 4 + q;
        const int hr = hrow_s[r];
        if (hr >= 0) {
          outw[(size_t)hr * O_DIM + (n0 + col)] = f2b(acc[i][j][q] + bb);
        }
      }
    }
  }
}

// ------------------------------------------------------------- softmax+y ----
__global__ __launch_bounds__(256) void softmax_y_kernel(
    const unsigned short* __restrict__ outw, const float* __restrict__ gate_bk,
    float* __restrict__ y)
{
  const int b = blockIdx.x, t = threadIdx.x;
  __shared__ float sred[4];
  float yacc[4] = {0.f, 0.f, 0.f, 0.f};
  for (int k = 0; k < K_TOP; ++k) {
    const unsigned short* __restrict__ row = outw + (size_t)(b * K_TOP + k) * O_DIM;
    float v[4];
    #pragma unroll
    for (int i = 0; i < 4; ++i) v[i] = b2f(row[t + i * 256]);
    float mx = fmaxf(fmaxf(v[0], v[1]), fmaxf(v[2], v[3]));
    #pragma unroll
    for (int off = 32; off >= 1; off >>= 1) mx = fmaxf(mx, __shfl_xor(mx, off, 64));
    if ((t & 63) == 0) sred[t >> 6] = mx;
    __syncthreads();
    mx = fmaxf(fmaxf(sred[0], sred[1]), fmaxf(sred[2], sred[3]));
    __syncthreads();
    float ex[4], ps = 0.f;
    #pragma unroll
    for (int i = 0; i < 4; ++i) { ex[i] = expf(v[i] - mx); ps += ex[i]; }
    #pragma unroll
    for (int off = 32; off >= 1; off >>= 1) ps += __shfl_xor(ps, off, 64);
    if ((t & 63) == 0) sred[t >> 6] = ps;
    __syncthreads();
    ps = sred[0] + sred[1] + sred[2] + sred[3];
    __syncthreads();
    const float g = gate_bk[b * K_TOP + k];
    const float inv = 1.f / ps;
    #pragma unroll
    for (int i = 0; i < 4; ++i) yacc[i] += g * expf(ex[i] * inv);
  }
  #pragma unroll
  for (int i = 0; i < 4; ++i) y[(size_t)b * O_DIM + t + i * 256] = yacc[i];
}

// ------------------------------------------------------------------ loss ----
__global__ __launch_bounds__(256) void loss_kernel(
    const float* __restrict__ gates_full, const float* __restrict__ prob_ws,
    float* __restrict__ out_loss)
{
  const int t = threadIdx.x;
  float imp[16], ld[16];
  #pragma unroll
  for (int e = 0; e < 16; ++e) { imp[e] = 0.f; ld[e] = 0.f; }
  for (int b = t; b < B_TOK; b += 256) {
    #pragma unroll
    for (int e = 0; e < 16; ++e) {
      imp[e] += gates_full[(size_t)b * E_NUM + e];
      ld[e]  += prob_ws[(size_t)b * E_NUM + e];
    }
  }
  #pragma unroll
  for (int e = 0; e < 16; ++e) {
    #pragma unroll
    for (int off = 32; off >= 1; off >>= 1) {
      imp[e] += __shfl_xor(imp[e], off, 64);
      ld[e]  += __shfl_xor(ld[e], off, 64);
    }
  }
  __shared__ float s_i[4][16], s_l[4][16];
  const int w = t >> 6, l = t & 63;
  if (l == 0) {
    #pragma unroll
    for (int e = 0; e < 16; ++e) { s_i[w][e] = imp[e]; s_l[w][e] = ld[e]; }
  }
  __syncthreads();
  if (t == 0) {
    float fi[16], fl[16], mi = 0.f, ml = 0.f;
    #pragma unroll
    for (int e = 0; e < 16; ++e) {
      fi[e] = s_i[0][e] + s_i[1][e] + s_i[2][e] + s_i[3][e];
      fl[e] = s_l[0][e] + s_l[1][e] + s_l[2][e] + s_l[3][e];
      mi += fi[e]; ml += fl[e];
    }
    mi *= (1.f / 16.f); ml *= (1.f / 16.f);
    float vi = 0.f, vl = 0.f;
    #pragma unroll
    for (int e = 0; e < 16; ++e) {
      const float di = fi[e] - mi, dl = fl[e] - ml;
      vi += di * di; vl += dl * dl;
    }
    vi *= (1.f / 15.f); vl *= (1.f / 15.f);
    const float loss = (vi / (mi * mi + 1e-10f) + vl / (ml * ml + 1e-10f)) * 0.01f;
    out_loss[0] = loss;
  }
}

// ---------------------------------------------------------------- launch ----
extern "C" void kernel_launch(void* const* d_in, const int* in_sizes, int n_in,
                              void* d_out, int out_size, void* d_ws, size_t ws_size,
                              hipStream_t stream)
{
  (void)in_sizes; (void)n_in; (void)out_size; (void)ws_size;
  const float* x       = (const float*)d_in[0];
  const float* noise   = (const float*)d_in[1];
  const float* w_gate  = (const float*)d_in[2];
  const float* w_noise = (const float*)d_in[3];
  const float* W1      = (const float*)d_in[4];
  const float* b1      = (const float*)d_in[5];
  const float* W2      = (const float*)d_in[6];
  const float* b2      = (const float*)d_in[7];
  float* out = (float*)d_out;

  char* wsc = (char*)d_ws;
  int*   counts     = (int*)wsc;                         // 16
  int*   pair_v     = counts + 16;                       // E*B
  float* gate_bk    = (float*)(pair_v + E_NUM * B_TOK);  // B*K
  float* gates_full = gate_bk + B_TOK * K_TOP;           // B*E
  float* prob_ws    = gates_full + B_TOK * E_NUM;        // B*E
  unsigned short* h    = (unsigned short*)(prob_ws + B_TOK * E_NUM); // B*K*H bf16
  unsigned short* outw = h + (size_t)B_TOK * K_TOP * H_DIM;          // B*K*O bf16

  hipMemsetAsync(counts, 0, 16 * sizeof(int), stream);
  gating_kernel<<<B_TOK, 256, 0, stream>>>(x, noise, w_gate, w_noise, counts,
                                           pair_v, gate_bk, gates_full, prob_ws);
  gemm1_kernel<<<dim3(B_TOK / BM, H_DIM / BN, E_NUM), 256, 0, stream>>>(
      x, W1, b1, counts, pair_v, h);
  gemm2_kernel<<<dim3(B_TOK / BM, O_DIM / BN, E_NUM), 256, 0, stream>>>(
      h, W2, b2, counts, pair_v, outw);
  softmax_y_kernel<<<B_TOK, 256, 0, stream>>>(outw, gate_bk, out);
  loss_kernel<<<1, 256, 0, stream>>>(gates_full, prob_ws,
                                     out + (size_t)B_TOK * O_DIM);
}

// Round 2
// 967.475 us; speedup vs baseline: 1.4072x; 1.4072x over previous
//
#include <hip/hip_runtime.h>
#include <math.h>

#define B_TOK 4096
#define D_DIM 1024
#define H_DIM 2048
#define O_DIM 1024
#define E_NUM 16
#define K_TOP 4

#define BM 128
#define BN 128
#define BK 32

typedef __attribute__((ext_vector_type(4))) float f32x4;
typedef __attribute__((ext_vector_type(8))) short bf16x8;
typedef __attribute__((ext_vector_type(4))) unsigned short u16x4;

__device__ __forceinline__ unsigned short f2b(float f) {
  unsigned u = __builtin_bit_cast(unsigned, f);
  u = u + 0x7FFFu + ((u >> 16) & 1u);
  return (unsigned short)(u >> 16);
}
__device__ __forceinline__ float b2f(unsigned short s) {
  return __builtin_bit_cast(float, ((unsigned)s) << 16);
}
__device__ __forceinline__ void async_load16(const unsigned short* g, unsigned short* l) {
  __builtin_amdgcn_global_load_lds(
      (const __attribute__((address_space(1))) unsigned int*)g,
      (__attribute__((address_space(3))) unsigned int*)l, 16, 0, 0);
}

// ---------------------------------------------------------------- gating ----
__global__ __launch_bounds__(256) void gating_kernel(
    const float* __restrict__ x, const float* __restrict__ noise,
    const float* __restrict__ w_gate, const float* __restrict__ w_noise,
    int* __restrict__ counts, int* __restrict__ pair_v,
    float* __restrict__ gate_bk, float* __restrict__ gates_full,
    float* __restrict__ prob_ws)
{
  const int b = blockIdx.x;
  const int t = threadIdx.x;
  const int e = t & 15, seg = t >> 4;           // 16 segs x 64 d each
  const float* __restrict__ xr = x + (size_t)b * D_DIM;

  float pg = 0.f, pn = 0.f;
  #pragma unroll 8
  for (int j = 0; j < 64; ++j) {
    const int d = seg * 64 + j;
    const float xv = xr[d];
    pg += xv * w_gate[d * E_NUM + e];
    pn += xv * w_noise[d * E_NUM + e];
  }
  __shared__ float sg[16][16], sn[16][16];
  sg[seg][e] = pg; sn[seg][e] = pn;
  __syncthreads();

  __shared__ float s_clean[16], s_std[16], s_noisy[16];
  if (t < 32) {
    const int which = t >> 4, ee = t & 15;
    float s = 0.f;
    #pragma unroll
    for (int i = 0; i < 16; ++i) s += which ? sn[i][ee] : sg[i][ee];
    if (which == 0) s_clean[ee] = s;
    else {
      const float sp = (s > 0.f) ? (s + log1pf(expf(-s))) : log1pf(expf(s));
      s_std[ee] = sp + 0.01f;
    }
  }
  __syncthreads();
  if (t < 16) s_noisy[t] = s_clean[t] + noise[(size_t)b * E_NUM + t] * s_std[t];
  __syncthreads();

  __shared__ float s_top[5];
  __shared__ int   s_idx[4];
  __shared__ float s_gates[4];
  if (t == 0) {
    float v[16];
    #pragma unroll
    for (int i = 0; i < 16; ++i) v[i] = s_noisy[i];
    unsigned mask = 0;
    float tv[5]; int ti[5];
    #pragma unroll
    for (int k = 0; k < 5; ++k) {
      float best = -3.4e38f; int bi = 0;
      #pragma unroll
      for (int i = 0; i < 16; ++i) {
        const bool ok = !((mask >> i) & 1u) && (v[i] > best);
        best = ok ? v[i] : best;
        bi   = ok ? i    : bi;
      }
      mask |= (1u << bi);
      tv[k] = best; ti[k] = bi;
    }
    const float m = tv[0];
    float ex[4], se = 0.f;
    #pragma unroll
    for (int k = 0; k < 4; ++k) { ex[k] = expf(tv[k] - m); se += ex[k]; }
    #pragma unroll
    for (int k = 0; k < 4; ++k) s_gates[k] = ex[k] / se;
    #pragma unroll
    for (int k = 0; k < 5; ++k) s_top[k] = tv[k];
    #pragma unroll
    for (int k = 0; k < 4; ++k) s_idx[k] = ti[k];
  }
  __syncthreads();

  if (t < 16) gates_full[(size_t)b * E_NUM + t] = 0.f;
  __syncthreads();
  if (t < 4) {
    const int ee = s_idx[t];
    const float g = s_gates[t];
    gate_bk[b * K_TOP + t] = g;
    gates_full[(size_t)b * E_NUM + ee] = g;
    const int slot = atomicAdd(&counts[ee], 1);
    pair_v[ee * B_TOK + slot] = b * K_TOP + t;     // h-row index = b*4 + rank
  }
  if (t < 16) {
    const float thr_in = s_top[4], thr_out = s_top[3];
    const float thr = (s_noisy[t] > thr_in) ? thr_in : thr_out;
    const float z = (s_clean[t] - thr) / s_std[t];
    prob_ws[(size_t)b * E_NUM + t] = 0.5f * (1.f + erff(z * 0.70710678118654752f));
  }
}

// ------------------------------------------------------------- convert x ----
__global__ __launch_bounds__(256) void convert_x_kernel(
    const float* __restrict__ x, unsigned short* __restrict__ xb)
{
  const size_t i = ((size_t)blockIdx.x * 256 + threadIdx.x) * 8;
  const f32x4 v0 = *(const f32x4*)&x[i];
  const f32x4 v1 = *(const f32x4*)&x[i + 4];
  bf16x8 o;
  #pragma unroll
  for (int q = 0; q < 4; ++q) { o[q] = (short)f2b(v0[q]); o[q + 4] = (short)f2b(v1[q]); }
  *(bf16x8*)&xb[i] = o;
}

// -------------------------------------------------- transpose fp32->bf16 ----
// in[e][R][C] fp32 -> out[e][C][R] bf16 ; 64x64 tiles
__global__ __launch_bounds__(256) void transpose_bf16_kernel(
    const float* __restrict__ in, unsigned short* __restrict__ out,
    int R, int C)
{
  const int e = blockIdx.z;
  const int c0 = blockIdx.x * 64;
  const int r0 = blockIdx.y * 64;
  __shared__ float tile[64][65];
  const int t = threadIdx.x;
  const int tr = t >> 4, tc4 = t & 15;
  const float* __restrict__ ip = in + (size_t)e * R * C;
  #pragma unroll
  for (int j = 0; j < 4; ++j) {
    const int rr = j * 16 + tr;
    const f32x4 v = *(const f32x4*)&ip[(size_t)(r0 + rr) * C + c0 + tc4 * 4];
    tile[rr][tc4 * 4 + 0] = v[0]; tile[rr][tc4 * 4 + 1] = v[1];
    tile[rr][tc4 * 4 + 2] = v[2]; tile[rr][tc4 * 4 + 3] = v[3];
  }
  __syncthreads();
  unsigned short* __restrict__ op = out + (size_t)e * R * C;
  #pragma unroll
  for (int j = 0; j < 4; ++j) {
    const int cc = j * 16 + tr;
    u16x4 o;
    o[0] = f2b(tile[tc4 * 4 + 0][cc]);
    o[1] = f2b(tile[tc4 * 4 + 1][cc]);
    o[2] = f2b(tile[tc4 * 4 + 2][cc]);
    o[3] = f2b(tile[tc4 * 4 + 3][cc]);
    *(u16x4*)&op[(size_t)(c0 + cc) * R + r0 + tc4 * 4] = o;
  }
}

// ------------------------------------------------------------------ GEMM ----
// Out[pair_row][n] = act( A[arow] @ Bt[e][n][:] + bias[e][n] )
// A: [*][KDIM] bf16 (x_bf or h); Bt: [E][NDIM][KDIM] bf16 (pre-transposed)
template<int NDIM, int KDIM, bool RELU, bool APAIR>
__global__ __launch_bounds__(256) void gemm_kernel(
    const unsigned short* __restrict__ A,
    const unsigned short* __restrict__ Bt,
    const float* __restrict__ biasE,
    const int* __restrict__ counts, const int* __restrict__ pair_v,
    unsigned short* __restrict__ Out)
{
  const int e = blockIdx.z;
  const int cnt = counts[e];
  const int m0 = blockIdx.x * BM;
  if (m0 >= cnt) return;
  const int n0 = blockIdx.y * BN;

  __shared__ __align__(16) unsigned short As[2][BM * BK];
  __shared__ __align__(16) unsigned short Bs[2][BN * BK];
  __shared__ int hrow_s[BM];

  const int t = threadIdx.x;
  const int w = t >> 6, l = t & 63;
  const int* __restrict__ plist = pair_v + e * B_TOK;
  if (t < BM) hrow_s[t] = (m0 + t < cnt) ? plist[m0 + t] : -1;
  __syncthreads();

  // staging geometry: issue i slot s = i*256 + w*64 + l ; LDS elem = s*8
  // row r = s>>2, chunk c = s&3 ; swizzle: slot c holds global chunk c^((r>>1)&3)
  const int r0 = w * 16 + (l >> 2);
  const int r1 = r0 + 64;
  const int c0 = l & 3;
  const int kc0 = (c0 ^ ((r0 >> 1) & 3)) * 8;
  const int kc1 = (c0 ^ ((r1 >> 1) & 3)) * 8;
  const int hv0 = hrow_s[r0], hv1 = hrow_s[r1];
  const size_t ar0 = (size_t)(hv0 < 0 ? 0 : (APAIR ? hv0 : (hv0 >> 2)));
  const size_t ar1 = (size_t)(hv1 < 0 ? 0 : (APAIR ? hv1 : (hv1 >> 2)));
  const unsigned short* __restrict__ aG0 = A + ar0 * KDIM + kc0;
  const unsigned short* __restrict__ aG1 = A + ar1 * KDIM + kc1;
  const unsigned short* __restrict__ bG0 = Bt + ((size_t)e * NDIM + n0 + r0) * KDIM + kc0;
  const unsigned short* __restrict__ bG1 = Bt + ((size_t)e * NDIM + n0 + r1) * KDIM + kc1;

  const int wm = (t >> 6) >> 1, wn = (t >> 6) & 1;
  const int gA = l >> 4;

  f32x4 acc[4][4];
  #pragma unroll
  for (int i = 0; i < 4; ++i)
    #pragma unroll
    for (int j = 0; j < 4; ++j)
      acc[i][j] = (f32x4){0.f, 0.f, 0.f, 0.f};

#define STAGE(bufi, kt) do {                                   \
    const int ko = (kt) * BK;                                  \
    async_load16(aG0 + ko, &As[bufi][w * 512]);                \
    async_load16(aG1 + ko, &As[bufi][2048 + w * 512]);         \
    async_load16(bG0 + ko, &Bs[bufi][w * 512]);                \
    async_load16(bG1 + ko, &Bs[bufi][2048 + w * 512]);         \
  } while (0)

  STAGE(0, 0);
  __syncthreads();                      // drains vmcnt+lgkmcnt before barrier

  int buf = 0;
  const int KITERS = KDIM / BK;
  for (int kt = 0; kt < KITERS; ++kt) {
    if (kt + 1 < KITERS) STAGE(buf ^ 1, kt + 1);   // async into other buffer
    bf16x8 af[4], bfr[4];
    #pragma unroll
    for (int i = 0; i < 4; ++i) {
      const int r = wm * 64 + i * 16 + (l & 15);
      af[i]  = *(const bf16x8*)&As[buf][r * BK + ((gA ^ ((r >> 1) & 3)) << 3)];
      const int c = wn * 64 + i * 16 + (l & 15);
      bfr[i] = *(const bf16x8*)&Bs[buf][c * BK + ((gA ^ ((c >> 1) & 3)) << 3)];
    }
    #pragma unroll
    for (int i = 0; i < 4; ++i)
      #pragma unroll
      for (int j = 0; j < 4; ++j)
        acc[i][j] = __builtin_amdgcn_mfma_f32_16x16x32_bf16(af[i], bfr[j], acc[i][j], 0, 0, 0);
    __syncthreads();                    // waits vmcnt(0): next buffer landed
    buf ^= 1;
  }
#undef STAGE

  const float* __restrict__ bias = biasE + (size_t)e * NDIM + n0;
  #pragma unroll
  for (int i = 0; i < 4; ++i) {
    #pragma unroll
    for (int j = 0; j < 4; ++j) {
      const int col = wn * 64 + j * 16 + (l & 15);
      const float bb = bias[col];
      #pragma unroll
      for (int q = 0; q < 4; ++q) {
        const int r = wm * 64 + i * 16 + gA * 4 + q;
        const int hr = hrow_s[r];
        if (hr >= 0) {
          float v = acc[i][j][q] + bb;
          if (RELU) v = v > 0.f ? v : 0.f;
          Out[(size_t)hr * NDIM + (n0 + col)] = f2b(v);
        }
      }
    }
  }
}

// ------------------------------------------------------------- softmax+y ----
__global__ __launch_bounds__(256) void softmax_y_kernel(
    const unsigned short* __restrict__ outw, const float* __restrict__ gate_bk,
    float* __restrict__ y)
{
  const int b = blockIdx.x, t = threadIdx.x;
  __shared__ float sred[4];
  float yacc[4] = {0.f, 0.f, 0.f, 0.f};
  for (int k = 0; k < K_TOP; ++k) {
    const unsigned short* __restrict__ row = outw + (size_t)(b * K_TOP + k) * O_DIM;
    float v[4];
    #pragma unroll
    for (int i = 0; i < 4; ++i) v[i] = b2f(row[t + i * 256]);
    float mx = fmaxf(fmaxf(v[0], v[1]), fmaxf(v[2], v[3]));
    #pragma unroll
    for (int off = 32; off >= 1; off >>= 1) mx = fmaxf(mx, __shfl_xor(mx, off, 64));
    if ((t & 63) == 0) sred[t >> 6] = mx;
    __syncthreads();
    mx = fmaxf(fmaxf(sred[0], sred[1]), fmaxf(sred[2], sred[3]));
    __syncthreads();
    float ex[4], ps = 0.f;
    #pragma unroll
    for (int i = 0; i < 4; ++i) { ex[i] = expf(v[i] - mx); ps += ex[i]; }
    #pragma unroll
    for (int off = 32; off >= 1; off >>= 1) ps += __shfl_xor(ps, off, 64);
    if ((t & 63) == 0) sred[t >> 6] = ps;
    __syncthreads();
    ps = sred[0] + sred[1] + sred[2] + sred[3];
    __syncthreads();
    const float g = gate_bk[b * K_TOP + k];
    const float inv = 1.f / ps;
    #pragma unroll
    for (int i = 0; i < 4; ++i) yacc[i] += g * expf(ex[i] * inv);
  }
  #pragma unroll
  for (int i = 0; i < 4; ++i) y[(size_t)b * O_DIM + t + i * 256] = yacc[i];
}

// ------------------------------------------------------------------ loss ----
__global__ __launch_bounds__(256) void loss_part_kernel(
    const float* __restrict__ gates_full, const float* __restrict__ prob_ws,
    float* __restrict__ part)   // [64][2][16]
{
  const int blk = blockIdx.x, t = threadIdx.x;
  const int e = t & 15, seg = t >> 4;
  float si = 0.f, sl = 0.f;
  #pragma unroll
  for (int j = 0; j < 4; ++j) {
    const int b = blk * 64 + seg * 4 + j;
    si += gates_full[(size_t)b * E_NUM + e];
    sl += prob_ws[(size_t)b * E_NUM + e];
  }
  __shared__ float li[16][16], ll[16][16];
  li[seg][e] = si; ll[seg][e] = sl;
  __syncthreads();
  if (t < 32) {
    const int which = t >> 4, ee = t & 15;
    float s = 0.f;
    #pragma unroll
    for (int i = 0; i < 16; ++i) s += which ? ll[i][ee] : li[i][ee];
    part[(blk * 2 + which) * 16 + ee] = s;
  }
}

__global__ __launch_bounds__(64) void loss_final_kernel(
    const float* __restrict__ part, float* __restrict__ out_loss)
{
  const int t = threadIdx.x;
  __shared__ float fi[16], fl[16];
  if (t < 32) {
    const int which = t >> 4, e = t & 15;
    float s = 0.f;
    for (int i = 0; i < 64; ++i) s += part[(i * 2 + which) * 16 + e];
    if (which) fl[e] = s; else fi[e] = s;
  }
  __syncthreads();
  if (t == 0) {
    float mi = 0.f, ml = 0.f;
    #pragma unroll
    for (int e = 0; e < 16; ++e) { mi += fi[e]; ml += fl[e]; }
    mi *= (1.f / 16.f); ml *= (1.f / 16.f);
    float vi = 0.f, vl = 0.f;
    #pragma unroll
    for (int e = 0; e < 16; ++e) {
      const float di = fi[e] - mi, dl = fl[e] - ml;
      vi += di * di; vl += dl * dl;
    }
    vi *= (1.f / 15.f); vl *= (1.f / 15.f);
    out_loss[0] = (vi / (mi * mi + 1e-10f) + vl / (ml * ml + 1e-10f)) * 0.01f;
  }
}

// ---------------------------------------------------------------- launch ----
extern "C" void kernel_launch(void* const* d_in, const int* in_sizes, int n_in,
                              void* d_out, int out_size, void* d_ws, size_t ws_size,
                              hipStream_t stream)
{
  (void)in_sizes; (void)n_in; (void)out_size; (void)ws_size;
  const float* x       = (const float*)d_in[0];
  const float* noise   = (const float*)d_in[1];
  const float* w_gate  = (const float*)d_in[2];
  const float* w_noise = (const float*)d_in[3];
  const float* W1      = (const float*)d_in[4];
  const float* b1      = (const float*)d_in[5];
  const float* W2      = (const float*)d_in[6];
  const float* b2      = (const float*)d_in[7];
  float* out = (float*)d_out;

  char* wsc = (char*)d_ws;
  int*   counts     = (int*)wsc;                          // 16
  int*   pair_v     = counts + 16;                        // E*B
  float* gate_bk    = (float*)(pair_v + E_NUM * B_TOK);   // B*K
  float* gates_full = gate_bk + B_TOK * K_TOP;            // B*E
  float* prob_ws    = gates_full + B_TOK * E_NUM;         // B*E
  float* part       = prob_ws + B_TOK * E_NUM;            // 64*2*16
  char* big = wsc + ((((char*)(part + 64 * 2 * 16) - wsc) + 255) & ~255);
  unsigned short* x_bf = (unsigned short*)big;                         // B*D bf16 (8MB)
  unsigned short* Wt   = x_bf + (size_t)B_TOK * D_DIM;                 // 67MB shared W1t/W2t
  unsigned short* h    = Wt + (size_t)E_NUM * D_DIM * H_DIM;           // B*K*H bf16 (67MB)
  unsigned short* outw = h + (size_t)B_TOK * K_TOP * H_DIM;            // B*K*O bf16 (34MB)

  hipMemsetAsync(counts, 0, 16 * sizeof(int), stream);
  gating_kernel<<<B_TOK, 256, 0, stream>>>(x, noise, w_gate, w_noise, counts,
                                           pair_v, gate_bk, gates_full, prob_ws);
  convert_x_kernel<<<(B_TOK * D_DIM / 8) / 256, 256, 0, stream>>>(x, x_bf);
  // W1 [e][D][H] -> W1t [e][H][D]
  transpose_bf16_kernel<<<dim3(H_DIM / 64, D_DIM / 64, E_NUM), 256, 0, stream>>>(
      W1, Wt, D_DIM, H_DIM);
  gemm_kernel<H_DIM, D_DIM, true, false><<<dim3(B_TOK / BM, H_DIM / BN, E_NUM), 256, 0, stream>>>(
      x_bf, Wt, b1, counts, pair_v, h);
  // W2 [e][H][O] -> W2t [e][O][H]  (reuses Wt region; gemm1 is done with it)
  transpose_bf16_kernel<<<dim3(O_DIM / 64, H_DIM / 64, E_NUM), 256, 0, stream>>>(
      W2, Wt, H_DIM, O_DIM);
  gemm_kernel<O_DIM, H_DIM, false, true><<<dim3(B_TOK / BM, O_DIM / BN, E_NUM), 256, 0, stream>>>(
      h, Wt, b2, counts, pair_v, outw);
  softmax_y_kernel<<<B_TOK, 256, 0, stream>>>(outw, gate_bk, out);
  loss_part_kernel<<<64, 256, 0, stream>>>(gates_full, prob_ws, part);
  loss_final_kernel<<<1, 64, 0, stream>>>(part, out + (size_t)B_TOK * O_DIM);
}

// Round 3
// 513.092 us; speedup vs baseline: 2.6535x; 1.8856x over previous
//
#include <hip/hip_runtime.h>
#include <math.h>

#define B_TOK 4096
#define D_DIM 1024
#define H_DIM 2048
#define O_DIM 1024
#define E_NUM 16
#define K_TOP 4

#define TBM 256
#define TBN 256
#define TBK 64

typedef __attribute__((ext_vector_type(4))) float f32x4;
typedef __attribute__((ext_vector_type(8))) short bf16x8;
typedef __attribute__((ext_vector_type(4))) unsigned short u16x4;

__device__ __forceinline__ unsigned short f2b(float f) {
  unsigned u = __builtin_bit_cast(unsigned, f);
  u = u + 0x7FFFu + ((u >> 16) & 1u);
  return (unsigned short)(u >> 16);
}
__device__ __forceinline__ float b2f(unsigned short s) {
  return __builtin_bit_cast(float, ((unsigned)s) << 16);
}
__device__ __forceinline__ void async_load16(const unsigned short* g, unsigned short* l) {
  __builtin_amdgcn_global_load_lds(
      (const __attribute__((address_space(1))) unsigned int*)g,
      (__attribute__((address_space(3))) unsigned int*)l, 16, 0, 0);
}

// ---------------------------------------------------------------- gating ----
__global__ __launch_bounds__(256) void gating_kernel(
    const float* __restrict__ x, const float* __restrict__ noise,
    const float* __restrict__ w_gate, const float* __restrict__ w_noise,
    int* __restrict__ counts, int* __restrict__ pair_v,
    float* __restrict__ gate_bk, float* __restrict__ gates_full,
    float* __restrict__ prob_ws)
{
  const int b = blockIdx.x;
  const int t = threadIdx.x;
  const int e = t & 15, seg = t >> 4;           // 16 segs x 64 d each
  const float* __restrict__ xr = x + (size_t)b * D_DIM;

  float pg = 0.f, pn = 0.f;
  #pragma unroll 8
  for (int j = 0; j < 64; ++j) {
    const int d = seg * 64 + j;
    const float xv = xr[d];
    pg += xv * w_gate[d * E_NUM + e];
    pn += xv * w_noise[d * E_NUM + e];
  }
  __shared__ float sg[16][16], sn[16][16];
  sg[seg][e] = pg; sn[seg][e] = pn;
  __syncthreads();

  __shared__ float s_clean[16], s_std[16], s_noisy[16];
  if (t < 32) {
    const int which = t >> 4, ee = t & 15;
    float s = 0.f;
    #pragma unroll
    for (int i = 0; i < 16; ++i) s += which ? sn[i][ee] : sg[i][ee];
    if (which == 0) s_clean[ee] = s;
    else {
      const float sp = (s > 0.f) ? (s + log1pf(expf(-s))) : log1pf(expf(s));
      s_std[ee] = sp + 0.01f;
    }
  }
  __syncthreads();
  if (t < 16) s_noisy[t] = s_clean[t] + noise[(size_t)b * E_NUM + t] * s_std[t];
  __syncthreads();

  __shared__ float s_top[5];
  __shared__ int   s_idx[4];
  __shared__ float s_gates[4];
  if (t == 0) {
    float v[16];
    #pragma unroll
    for (int i = 0; i < 16; ++i) v[i] = s_noisy[i];
    unsigned mask = 0;
    float tv[5]; int ti[5];
    #pragma unroll
    for (int k = 0; k < 5; ++k) {
      float best = -3.4e38f; int bi = 0;
      #pragma unroll
      for (int i = 0; i < 16; ++i) {
        const bool ok = !((mask >> i) & 1u) && (v[i] > best);
        best = ok ? v[i] : best;
        bi   = ok ? i    : bi;
      }
      mask |= (1u << bi);
      tv[k] = best; ti[k] = bi;
    }
    const float m = tv[0];
    float ex[4], se = 0.f;
    #pragma unroll
    for (int k = 0; k < 4; ++k) { ex[k] = expf(tv[k] - m); se += ex[k]; }
    #pragma unroll
    for (int k = 0; k < 4; ++k) s_gates[k] = ex[k] / se;
    #pragma unroll
    for (int k = 0; k < 5; ++k) s_top[k] = tv[k];
    #pragma unroll
    for (int k = 0; k < 4; ++k) s_idx[k] = ti[k];
  }
  __syncthreads();

  if (t < 16) gates_full[(size_t)b * E_NUM + t] = 0.f;
  __syncthreads();
  if (t < 4) {
    const int ee = s_idx[t];
    const float g = s_gates[t];
    gate_bk[b * K_TOP + t] = g;
    gates_full[(size_t)b * E_NUM + ee] = g;
    const int slot = atomicAdd(&counts[ee], 1);
    pair_v[ee * B_TOK + slot] = b * K_TOP + t;     // h-row index = b*4 + rank
  }
  if (t < 16) {
    const float thr_in = s_top[4], thr_out = s_top[3];
    const float thr = (s_noisy[t] > thr_in) ? thr_in : thr_out;
    const float z = (s_clean[t] - thr) / s_std[t];
    prob_ws[(size_t)b * E_NUM + t] = 0.5f * (1.f + erff(z * 0.70710678118654752f));
  }
}

// ------------------------------------------------------------- convert x ----
__global__ __launch_bounds__(256) void convert_x_kernel(
    const float* __restrict__ x, unsigned short* __restrict__ xb)
{
  const size_t i = ((size_t)blockIdx.x * 256 + threadIdx.x) * 8;
  const f32x4 v0 = *(const f32x4*)&x[i];
  const f32x4 v1 = *(const f32x4*)&x[i + 4];
  bf16x8 o;
  #pragma unroll
  for (int q = 0; q < 4; ++q) { o[q] = (short)f2b(v0[q]); o[q + 4] = (short)f2b(v1[q]); }
  *(bf16x8*)&xb[i] = o;
}

// -------------------------------------------------- transpose fp32->bf16 ----
// in[e][R][C] fp32 -> out[e][C][R] bf16 ; 64x64 tiles
__global__ __launch_bounds__(256) void transpose_bf16_kernel(
    const float* __restrict__ in, unsigned short* __restrict__ out,
    int R, int C)
{
  const int e = blockIdx.z;
  const int c0 = blockIdx.x * 64;
  const int r0 = blockIdx.y * 64;
  __shared__ float tile[64][65];
  const int t = threadIdx.x;
  const int tr = t >> 4, tc4 = t & 15;
  const float* __restrict__ ip = in + (size_t)e * R * C;
  #pragma unroll
  for (int j = 0; j < 4; ++j) {
    const int rr = j * 16 + tr;
    const f32x4 v = *(const f32x4*)&ip[(size_t)(r0 + rr) * C + c0 + tc4 * 4];
    tile[rr][tc4 * 4 + 0] = v[0]; tile[rr][tc4 * 4 + 1] = v[1];
    tile[rr][tc4 * 4 + 2] = v[2]; tile[rr][tc4 * 4 + 3] = v[3];
  }
  __syncthreads();
  unsigned short* __restrict__ op = out + (size_t)e * R * C;
  #pragma unroll
  for (int j = 0; j < 4; ++j) {
    const int cc = j * 16 + tr;
    u16x4 o;
    o[0] = f2b(tile[tc4 * 4 + 0][cc]);
    o[1] = f2b(tile[tc4 * 4 + 1][cc]);
    o[2] = f2b(tile[tc4 * 4 + 2][cc]);
    o[3] = f2b(tile[tc4 * 4 + 3][cc]);
    *(u16x4*)&op[(size_t)(c0 + cc) * R + r0 + tc4 * 4] = o;
  }
}

// ------------------------------------------------------------ GEMM 256² ----
// Out[pair_row][n] = act( A[arow] @ Bt[e][n][:] + bias[e][n] ), grouped by e.
// 512 threads = 8 waves (2 wr x 4 wc); per-wave output 128x64.
// LDS: 2 x (256x64) bf16 for A and B = 128 KB double-buffered.
// Swizzle: 16B chunk c of row r holds global chunk c ^ (r&7) (involution);
// applied on the global source (gload_lds dest stays linear) and on ds_read.
template<int NDIM, int KDIM, bool RELU, bool APAIR>
__global__ __launch_bounds__(512, 2) void gemm256_kernel(
    const unsigned short* __restrict__ A,
    const unsigned short* __restrict__ Bt,
    const float* __restrict__ biasE,
    const int* __restrict__ counts, const int* __restrict__ pair_v,
    unsigned short* __restrict__ Out)
{
  constexpr int GX = B_TOK / TBM;        // 16
  constexpr int GY = NDIM / TBN;
  constexpr int TOT = GX * GY * E_NUM;   // divisible by 8
  const int bid = blockIdx.x;
  const int wg = (bid & 7) * (TOT / 8) + (bid >> 3);   // chunked XCD swizzle
  const int mx = wg % GX;
  const int ny = (wg / GX) % GY;
  const int e  = wg / (GX * GY);

  const int cnt = counts[e];
  const int m0 = mx * TBM;
  if (m0 >= cnt) return;
  const int n0 = ny * TBN;

  __shared__ __align__(16) unsigned short As[2][TBM * TBK];   // 2 x 32 KB
  __shared__ __align__(16) unsigned short Bs[2][TBN * TBK];   // 2 x 32 KB

  const int t = threadIdx.x;
  const int w = t >> 6, l = t & 63;
  const int* __restrict__ plist = pair_v + e * B_TOK;

  // ---- staging geometry: slot s = i*512 + w*64 + l ; row r = s>>3, chunk
  // c = s&7 ; LDS byte = s*16 (linear). Global chunk gc = c ^ (r&7).
  // r&7 == l>>3 and c == l&7 for all issues i -> gc is issue-invariant.
  const int gc = (l & 7) ^ (l >> 3);
  const unsigned short* aG[4];
  const unsigned short* bG[4];
  #pragma unroll
  for (int i = 0; i < 4; ++i) {
    const int r = i * 64 + w * 8 + (l >> 3);
    const int pr = (m0 + r < cnt) ? plist[m0 + r] : -1;
    const size_t tok = (size_t)(pr < 0 ? 0 : (APAIR ? pr : (pr >> 2)));
    aG[i] = A + tok * KDIM + gc * 8;
    bG[i] = Bt + ((size_t)e * NDIM + n0 + r) * KDIM + gc * 8;
  }

#define STAGE(bufi, kt) do {                                        \
    const int ko_ = (kt) * TBK;                                     \
    _Pragma("unroll")                                               \
    for (int i_ = 0; i_ < 4; ++i_) {                                \
      async_load16(aG[i_] + ko_, &As[bufi][i_ * 4096 + w * 512]);   \
      async_load16(bG[i_] + ko_, &Bs[bufi][i_ * 4096 + w * 512]);   \
    }                                                               \
  } while (0)

  const int wr = w >> 2, wc = w & 3;
  const int lr = l & 15, gA = l >> 4;

  f32x4 acc[8][4];
  #pragma unroll
  for (int i = 0; i < 8; ++i)
    #pragma unroll
    for (int j = 0; j < 4; ++j)
      acc[i][j] = (f32x4){0.f, 0.f, 0.f, 0.f};

  STAGE(0, 0);
  __syncthreads();                       // drains vmcnt(0): buf0 ready

  int buf = 0;
  constexpr int KIT = KDIM / TBK;
  for (int kt = 0; kt < KIT; ++kt) {
    if (kt + 1 < KIT) STAGE(buf ^ 1, kt + 1);   // async into other buffer
    #pragma unroll
    for (int ks = 0; ks < 2; ++ks) {
      bf16x8 a[8], bv[4];
      #pragma unroll
      for (int i = 0; i < 8; ++i) {
        const int ra = wr * 128 + i * 16 + lr;
        const int ca = ks * 4 + gA;
        a[i] = *(const bf16x8*)&As[buf][ra * 64 + ((ca ^ (ra & 7)) << 3)];
      }
      #pragma unroll
      for (int j = 0; j < 4; ++j) {
        const int rb = wc * 64 + j * 16 + lr;
        const int cb = ks * 4 + gA;
        bv[j] = *(const bf16x8*)&Bs[buf][rb * 64 + ((cb ^ (rb & 7)) << 3)];
      }
      #pragma unroll
      for (int i = 0; i < 8; ++i)
        #pragma unroll
        for (int j = 0; j < 4; ++j)
          acc[i][j] = __builtin_amdgcn_mfma_f32_16x16x32_bf16(a[i], bv[j], acc[i][j], 0, 0, 0);
    }
    __syncthreads();                     // waits vmcnt(0): next buffer landed
    buf ^= 1;
  }
#undef STAGE

  const float* __restrict__ bias = biasE + (size_t)e * NDIM + n0;
  #pragma unroll
  for (int i = 0; i < 8; ++i) {
    #pragma unroll
    for (int q = 0; q < 4; ++q) {
      const int rl = wr * 128 + i * 16 + gA * 4 + q;
      if (m0 + rl < cnt) {
        const int pr = plist[m0 + rl];
        #pragma unroll
        for (int j = 0; j < 4; ++j) {
          const int col = wc * 64 + j * 16 + lr;
          float v = acc[i][j][q] + bias[col];
          if (RELU) v = v > 0.f ? v : 0.f;
          Out[(size_t)pr * NDIM + n0 + col] = f2b(v);
        }
      }
    }
  }
}

// ------------------------------------------------------------- softmax+y ----
__global__ __launch_bounds__(256) void softmax_y_kernel(
    const unsigned short* __restrict__ outw, const float* __restrict__ gate_bk,
    float* __restrict__ y)
{
  const int b = blockIdx.x, t = threadIdx.x;
  __shared__ float sred[4];
  float yacc[4] = {0.f, 0.f, 0.f, 0.f};
  for (int k = 0; k < K_TOP; ++k) {
    const unsigned short* __restrict__ row = outw + (size_t)(b * K_TOP + k) * O_DIM;
    float v[4];
    #pragma unroll
    for (int i = 0; i < 4; ++i) v[i] = b2f(row[t + i * 256]);
    float mx = fmaxf(fmaxf(v[0], v[1]), fmaxf(v[2], v[3]));
    #pragma unroll
    for (int off = 32; off >= 1; off >>= 1) mx = fmaxf(mx, __shfl_xor(mx, off, 64));
    if ((t & 63) == 0) sred[t >> 6] = mx;
    __syncthreads();
    mx = fmaxf(fmaxf(sred[0], sred[1]), fmaxf(sred[2], sred[3]));
    __syncthreads();
    float ex[4], ps = 0.f;
    #pragma unroll
    for (int i = 0; i < 4; ++i) { ex[i] = expf(v[i] - mx); ps += ex[i]; }
    #pragma unroll
    for (int off = 32; off >= 1; off >>= 1) ps += __shfl_xor(ps, off, 64);
    if ((t & 63) == 0) sred[t >> 6] = ps;
    __syncthreads();
    ps = sred[0] + sred[1] + sred[2] + sred[3];
    __syncthreads();
    const float g = gate_bk[b * K_TOP + k];
    const float inv = 1.f / ps;
    #pragma unroll
    for (int i = 0; i < 4; ++i) yacc[i] += g * expf(ex[i] * inv);
  }
  #pragma unroll
  for (int i = 0; i < 4; ++i) y[(size_t)b * O_DIM + t + i * 256] = yacc[i];
}

// ------------------------------------------------------------------ loss ----
__global__ __launch_bounds__(256) void loss_part_kernel(
    const float* __restrict__ gates_full, const float* __restrict__ prob_ws,
    float* __restrict__ part)   // [64][2][16]
{
  const int blk = blockIdx.x, t = threadIdx.x;
  const int e = t & 15, seg = t >> 4;
  float si = 0.f, sl = 0.f;
  #pragma unroll
  for (int j = 0; j < 4; ++j) {
    const int b = blk * 64 + seg * 4 + j;
    si += gates_full[(size_t)b * E_NUM + e];
    sl += prob_ws[(size_t)b * E_NUM + e];
  }
  __shared__ float li[16][16], ll[16][16];
  li[seg][e] = si; ll[seg][e] = sl;
  __syncthreads();
  if (t < 32) {
    const int which = t >> 4, ee = t & 15;
    float s = 0.f;
    #pragma unroll
    for (int i = 0; i < 16; ++i) s += which ? ll[i][ee] : li[i][ee];
    part[(blk * 2 + which) * 16 + ee] = s;
  }
}

__global__ __launch_bounds__(64) void loss_final_kernel(
    const float* __restrict__ part, float* __restrict__ out_loss)
{
  const int t = threadIdx.x;
  __shared__ float fi[16], fl[16];
  if (t < 32) {
    const int which = t >> 4, e = t & 15;
    float s = 0.f;
    for (int i = 0; i < 64; ++i) s += part[(i * 2 + which) * 16 + e];
    if (which) fl[e] = s; else fi[e] = s;
  }
  __syncthreads();
  if (t == 0) {
    float mi = 0.f, ml = 0.f;
    #pragma unroll
    for (int e = 0; e < 16; ++e) { mi += fi[e]; ml += fl[e]; }
    mi *= (1.f / 16.f); ml *= (1.f / 16.f);
    float vi = 0.f, vl = 0.f;
    #pragma unroll
    for (int e = 0; e < 16; ++e) {
      const float di = fi[e] - mi, dl = fl[e] - ml;
      vi += di * di; vl += dl * dl;
    }
    vi *= (1.f / 15.f); vl *= (1.f / 15.f);
    out_loss[0] = (vi / (mi * mi + 1e-10f) + vl / (ml * ml + 1e-10f)) * 0.01f;
  }
}

// ---------------------------------------------------------------- launch ----
extern "C" void kernel_launch(void* const* d_in, const int* in_sizes, int n_in,
                              void* d_out, int out_size, void* d_ws, size_t ws_size,
                              hipStream_t stream)
{
  (void)in_sizes; (void)n_in; (void)out_size; (void)ws_size;
  const float* x       = (const float*)d_in[0];
  const float* noise   = (const float*)d_in[1];
  const float* w_gate  = (const float*)d_in[2];
  const float* w_noise = (const float*)d_in[3];
  const float* W1      = (const float*)d_in[4];
  const float* b1      = (const float*)d_in[5];
  const float* W2      = (const float*)d_in[6];
  const float* b2      = (const float*)d_in[7];
  float* out = (float*)d_out;

  char* wsc = (char*)d_ws;
  int*   counts     = (int*)wsc;                          // 16
  int*   pair_v     = counts + 16;                        // E*B
  float* gate_bk    = (float*)(pair_v + E_NUM * B_TOK);   // B*K
  float* gates_full = gate_bk + B_TOK * K_TOP;            // B*E
  float* prob_ws    = gates_full + B_TOK * E_NUM;         // B*E
  float* part       = prob_ws + B_TOK * E_NUM;            // 64*2*16
  char* big = wsc + ((((char*)(part + 64 * 2 * 16) - wsc) + 255) & ~255);
  unsigned short* x_bf = (unsigned short*)big;                         // B*D bf16 (8MB)
  unsigned short* Wt   = x_bf + (size_t)B_TOK * D_DIM;                 // 67MB shared W1t/W2t
  unsigned short* h    = Wt + (size_t)E_NUM * D_DIM * H_DIM;           // B*K*H bf16 (67MB)
  unsigned short* outw = h + (size_t)B_TOK * K_TOP * H_DIM;            // B*K*O bf16 (34MB)

  hipMemsetAsync(counts, 0, 16 * sizeof(int), stream);
  gating_kernel<<<B_TOK, 256, 0, stream>>>(x, noise, w_gate, w_noise, counts,
                                           pair_v, gate_bk, gates_full, prob_ws);
  convert_x_kernel<<<(B_TOK * D_DIM / 8) / 256, 256, 0, stream>>>(x, x_bf);
  // W1 [e][D][H] -> W1t [e][H][D]
  transpose_bf16_kernel<<<dim3(H_DIM / 64, D_DIM / 64, E_NUM), 256, 0, stream>>>(
      W1, Wt, D_DIM, H_DIM);
  gemm256_kernel<H_DIM, D_DIM, true, false>
      <<<dim3((B_TOK / TBM) * (H_DIM / TBN) * E_NUM), 512, 0, stream>>>(
      x_bf, Wt, b1, counts, pair_v, h);
  // W2 [e][H][O] -> W2t [e][O][H]  (reuses Wt region; gemm1 is done with it)
  transpose_bf16_kernel<<<dim3(O_DIM / 64, H_DIM / 64, E_NUM), 256, 0, stream>>>(
      W2, Wt, H_DIM, O_DIM);
  gemm256_kernel<O_DIM, H_DIM, false, true>
      <<<dim3((B_TOK / TBM) * (O_DIM / TBN) * E_NUM), 512, 0, stream>>>(
      h, Wt, b2, counts, pair_v, outw);
  softmax_y_kernel<<<B_TOK, 256, 0, stream>>>(outw, gate_bk, out);
  loss_part_kernel<<<64, 256, 0, stream>>>(gates_full, prob_ws, part);
  loss_final_kernel<<<1, 64, 0, stream>>>(part, out + (size_t)B_TOK * O_DIM);
}

// Round 4
// 473.763 us; speedup vs baseline: 2.8737x; 1.0830x over previous
//
#include <hip/hip_runtime.h>
#include <math.h>

#define B_TOK 4096
#define D_DIM 1024
#define H_DIM 2048
#define O_DIM 1024
#define E_NUM 16
#define K_TOP 4

#define TBM 256
#define TBN 256
#define TBK 64

typedef __attribute__((ext_vector_type(4))) float f32x4;
typedef __attribute__((ext_vector_type(8))) short bf16x8;
typedef __attribute__((ext_vector_type(4))) unsigned short u16x4;

__device__ __forceinline__ unsigned short f2b(float f) {
  unsigned u = __builtin_bit_cast(unsigned, f);
  u = u + 0x7FFFu + ((u >> 16) & 1u);
  return (unsigned short)(u >> 16);
}
__device__ __forceinline__ float b2f(unsigned short s) {
  return __builtin_bit_cast(float, ((unsigned)s) << 16);
}
__device__ __forceinline__ void async_load16(const unsigned short* g, unsigned short* l) {
  __builtin_amdgcn_global_load_lds(
      (const __attribute__((address_space(1))) unsigned int*)g,
      (__attribute__((address_space(3))) unsigned int*)l, 16, 0, 0);
}

// ---------------------------------------------------------------- gating ----
__global__ __launch_bounds__(256) void gating_kernel(
    const float* __restrict__ x, const float* __restrict__ noise,
    const float* __restrict__ w_gate, const float* __restrict__ w_noise,
    int* __restrict__ counts, int* __restrict__ pair_v,
    float* __restrict__ gate_bk, float* __restrict__ gates_full,
    float* __restrict__ prob_ws)
{
  const int b = blockIdx.x;
  const int t = threadIdx.x;
  const int e = t & 15, seg = t >> 4;           // 16 segs x 64 d each
  const float* __restrict__ xr = x + (size_t)b * D_DIM;

  float pg = 0.f, pn = 0.f;
  #pragma unroll 8
  for (int j = 0; j < 64; ++j) {
    const int d = seg * 64 + j;
    const float xv = xr[d];
    pg += xv * w_gate[d * E_NUM + e];
    pn += xv * w_noise[d * E_NUM + e];
  }
  __shared__ float sg[16][16], sn[16][16];
  sg[seg][e] = pg; sn[seg][e] = pn;
  __syncthreads();

  __shared__ float s_clean[16], s_std[16], s_noisy[16];
  if (t < 32) {
    const int which = t >> 4, ee = t & 15;
    float s = 0.f;
    #pragma unroll
    for (int i = 0; i < 16; ++i) s += which ? sn[i][ee] : sg[i][ee];
    if (which == 0) s_clean[ee] = s;
    else {
      const float sp = (s > 0.f) ? (s + log1pf(expf(-s))) : log1pf(expf(s));
      s_std[ee] = sp + 0.01f;
    }
  }
  __syncthreads();
  if (t < 16) s_noisy[t] = s_clean[t] + noise[(size_t)b * E_NUM + t] * s_std[t];
  __syncthreads();

  __shared__ float s_top[5];
  __shared__ int   s_idx[4];
  __shared__ float s_gates[4];
  if (t == 0) {
    float v[16];
    #pragma unroll
    for (int i = 0; i < 16; ++i) v[i] = s_noisy[i];
    unsigned mask = 0;
    float tv[5]; int ti[5];
    #pragma unroll
    for (int k = 0; k < 5; ++k) {
      float best = -3.4e38f; int bi = 0;
      #pragma unroll
      for (int i = 0; i < 16; ++i) {
        const bool ok = !((mask >> i) & 1u) && (v[i] > best);
        best = ok ? v[i] : best;
        bi   = ok ? i    : bi;
      }
      mask |= (1u << bi);
      tv[k] = best; ti[k] = bi;
    }
    const float m = tv[0];
    float ex[4], se = 0.f;
    #pragma unroll
    for (int k = 0; k < 4; ++k) { ex[k] = expf(tv[k] - m); se += ex[k]; }
    #pragma unroll
    for (int k = 0; k < 4; ++k) s_gates[k] = ex[k] / se;
    #pragma unroll
    for (int k = 0; k < 5; ++k) s_top[k] = tv[k];
    #pragma unroll
    for (int k = 0; k < 4; ++k) s_idx[k] = ti[k];
  }
  __syncthreads();

  if (t < 16) gates_full[(size_t)b * E_NUM + t] = 0.f;
  __syncthreads();
  if (t < 4) {
    const int ee = s_idx[t];
    const float g = s_gates[t];
    gate_bk[b * K_TOP + t] = g;
    gates_full[(size_t)b * E_NUM + ee] = g;
    const int slot = atomicAdd(&counts[ee], 1);
    pair_v[ee * B_TOK + slot] = b * K_TOP + t;     // h-row index = b*4 + rank
  }
  if (t < 16) {
    const float thr_in = s_top[4], thr_out = s_top[3];
    const float thr = (s_noisy[t] > thr_in) ? thr_in : thr_out;
    const float z = (s_clean[t] - thr) / s_std[t];
    prob_ws[(size_t)b * E_NUM + t] = 0.5f * (1.f + erff(z * 0.70710678118654752f));
  }
}

// -------------------------------------------------------------- prep tasks --
// Builds compacted active-tile lists for both GEMMs from counts.
__global__ void prep_tasks_kernel(const int* __restrict__ counts,
                                  int* __restrict__ tasks1, int* __restrict__ meta)
{
  if (threadIdx.x == 0) {
    int* tasks2 = tasks1 + 1024;
    int k1 = 0, k2 = 0;
    for (int e = 0; e < E_NUM; ++e) {
      const int mb = (counts[e] + TBM - 1) / TBM;
      for (int m = 0; m < mb; ++m) {
        for (int nb = 0; nb < H_DIM / TBN; ++nb)
          tasks1[k1++] = (e << 16) | (m << 8) | nb;
        for (int nb = 0; nb < O_DIM / TBN; ++nb)
          tasks2[k2++] = (e << 16) | (m << 8) | nb;
      }
    }
    meta[0] = k1;   // n_tasks1
    meta[1] = k2;   // n_tasks2
  }
}

// ------------------------------------------------------------- convert x ----
__global__ __launch_bounds__(256) void convert_x_kernel(
    const float* __restrict__ x, unsigned short* __restrict__ xb)
{
  const size_t i = ((size_t)blockIdx.x * 256 + threadIdx.x) * 8;
  const f32x4 v0 = *(const f32x4*)&x[i];
  const f32x4 v1 = *(const f32x4*)&x[i + 4];
  bf16x8 o;
  #pragma unroll
  for (int q = 0; q < 4; ++q) { o[q] = (short)f2b(v0[q]); o[q + 4] = (short)f2b(v1[q]); }
  *(bf16x8*)&xb[i] = o;
}

// -------------------------------------------------- transpose fp32->bf16 ----
// in[e][R][C] fp32 -> out[e][C][R] bf16 ; 64x64 tiles
__global__ __launch_bounds__(256) void transpose_bf16_kernel(
    const float* __restrict__ in, unsigned short* __restrict__ out,
    int R, int C)
{
  const int e = blockIdx.z;
  const int c0 = blockIdx.x * 64;
  const int r0 = blockIdx.y * 64;
  __shared__ float tile[64][65];
  const int t = threadIdx.x;
  const int tr = t >> 4, tc4 = t & 15;
  const float* __restrict__ ip = in + (size_t)e * R * C;
  #pragma unroll
  for (int j = 0; j < 4; ++j) {
    const int rr = j * 16 + tr;
    const f32x4 v = *(const f32x4*)&ip[(size_t)(r0 + rr) * C + c0 + tc4 * 4];
    tile[rr][tc4 * 4 + 0] = v[0]; tile[rr][tc4 * 4 + 1] = v[1];
    tile[rr][tc4 * 4 + 2] = v[2]; tile[rr][tc4 * 4 + 3] = v[3];
  }
  __syncthreads();
  unsigned short* __restrict__ op = out + (size_t)e * R * C;
  #pragma unroll
  for (int j = 0; j < 4; ++j) {
    const int cc = j * 16 + tr;
    u16x4 o;
    o[0] = f2b(tile[tc4 * 4 + 0][cc]);
    o[1] = f2b(tile[tc4 * 4 + 1][cc]);
    o[2] = f2b(tile[tc4 * 4 + 2][cc]);
    o[3] = f2b(tile[tc4 * 4 + 3][cc]);
    *(u16x4*)&op[(size_t)(c0 + cc) * R + r0 + tc4 * 4] = o;
  }
}

// -------------------------------------- GEMM 256², persistent work-steal ----
// 256 blocks (1/CU) pull active tiles from a global atomic counter.
// Inner structure identical to R3: 8 waves (2x4), 128 KB dbuf LDS,
// chunk-XOR swizzle (involution on global source + ds_read; LDS dest linear).
template<int NDIM, int KDIM, bool RELU, bool APAIR>
__global__ __launch_bounds__(512, 1) void gemm256p_kernel(
    const unsigned short* __restrict__ A,
    const unsigned short* __restrict__ Bt,
    const float* __restrict__ biasE,
    const int* __restrict__ counts, const int* __restrict__ pair_v,
    const int* __restrict__ tasks, const int* __restrict__ n_tasks_p,
    int* __restrict__ task_ctr,
    unsigned short* __restrict__ Out)
{
  __shared__ __align__(16) unsigned short As[2][TBM * TBK];   // 2 x 32 KB
  __shared__ __align__(16) unsigned short Bs[2][TBN * TBK];   // 2 x 32 KB
  __shared__ int s_task;

  const int t = threadIdx.x;
  const int w = t >> 6, l = t & 63;
  const int n_tasks = *n_tasks_p;

  const int gc = (l & 7) ^ (l >> 3);       // issue-invariant global chunk
  const int wr = w >> 2, wc = w & 3;
  const int lr = l & 15, gA = l >> 4;

  for (;;) {
    if (t == 0) s_task = atomicAdd(task_ctr, 1);
    __syncthreads();
    const int task = s_task;
    if (task >= n_tasks) break;

    const int tk = tasks[task];
    const int e  = tk >> 16;
    const int m0 = ((tk >> 8) & 255) * TBM;
    const int n0 = (tk & 255) * TBN;
    const int cnt = counts[e];
    const int* __restrict__ plist = pair_v + e * B_TOK;

    // staging geometry: slot s = i*512 + w*64 + l ; row r = s>>3, chunk c=s&7;
    // LDS byte = s*16 (linear). Global chunk gc = c ^ (r&7).
    const unsigned short* aG[4];
    const unsigned short* bG[4];
    #pragma unroll
    for (int i = 0; i < 4; ++i) {
      const int r = i * 64 + w * 8 + (l >> 3);
      const int pr = (m0 + r < cnt) ? plist[m0 + r] : -1;
      const size_t tok = (size_t)(pr < 0 ? 0 : (APAIR ? pr : (pr >> 2)));
      aG[i] = A + tok * KDIM + gc * 8;
      bG[i] = Bt + ((size_t)e * NDIM + n0 + r) * KDIM + gc * 8;
    }

#define STAGE(bufi, kt) do {                                        \
    const int ko_ = (kt) * TBK;                                     \
    _Pragma("unroll")                                               \
    for (int i_ = 0; i_ < 4; ++i_) {                                \
      async_load16(aG[i_] + ko_, &As[bufi][i_ * 4096 + w * 512]);   \
      async_load16(bG[i_] + ko_, &Bs[bufi][i_ * 4096 + w * 512]);   \
    }                                                               \
  } while (0)

    f32x4 acc[8][4];
    #pragma unroll
    for (int i = 0; i < 8; ++i)
      #pragma unroll
      for (int j = 0; j < 4; ++j)
        acc[i][j] = (f32x4){0.f, 0.f, 0.f, 0.f};

    STAGE(0, 0);
    __syncthreads();                      // drains vmcnt(0): buf0 ready

    int buf = 0;
    constexpr int KIT = KDIM / TBK;
    for (int kt = 0; kt < KIT; ++kt) {
      if (kt + 1 < KIT) STAGE(buf ^ 1, kt + 1);   // async into other buffer
      #pragma unroll
      for (int ks = 0; ks < 2; ++ks) {
        bf16x8 a[8], bv[4];
        #pragma unroll
        for (int i = 0; i < 8; ++i) {
          const int ra = wr * 128 + i * 16 + lr;
          const int ca = ks * 4 + gA;
          a[i] = *(const bf16x8*)&As[buf][ra * 64 + ((ca ^ (ra & 7)) << 3)];
        }
        #pragma unroll
        for (int j = 0; j < 4; ++j) {
          const int rb = wc * 64 + j * 16 + lr;
          const int cb = ks * 4 + gA;
          bv[j] = *(const bf16x8*)&Bs[buf][rb * 64 + ((cb ^ (rb & 7)) << 3)];
        }
        #pragma unroll
        for (int i = 0; i < 8; ++i)
          #pragma unroll
          for (int j = 0; j < 4; ++j)
            acc[i][j] = __builtin_amdgcn_mfma_f32_16x16x32_bf16(a[i], bv[j], acc[i][j], 0, 0, 0);
      }
      __syncthreads();                    // waits vmcnt(0): next buffer landed
      buf ^= 1;
    }
#undef STAGE

    const float* __restrict__ bias = biasE + (size_t)e * NDIM + n0;
    #pragma unroll
    for (int i = 0; i < 8; ++i) {
      #pragma unroll
      for (int q = 0; q < 4; ++q) {
        const int rl = wr * 128 + i * 16 + gA * 4 + q;
        if (m0 + rl < cnt) {
          const int pr = plist[m0 + rl];
          #pragma unroll
          for (int j = 0; j < 4; ++j) {
            const int col = wc * 64 + j * 16 + lr;
            float v = acc[i][j][q] + bias[col];
            if (RELU) v = v > 0.f ? v : 0.f;
            Out[(size_t)pr * NDIM + n0 + col] = f2b(v);
          }
        }
      }
    }
  }
}

// ------------------------------------------------------------- softmax+y ----
__global__ __launch_bounds__(256) void softmax_y_kernel(
    const unsigned short* __restrict__ outw, const float* __restrict__ gate_bk,
    float* __restrict__ y)
{
  const int b = blockIdx.x, t = threadIdx.x;
  __shared__ float sred[4];
  float yacc[4] = {0.f, 0.f, 0.f, 0.f};
  for (int k = 0; k < K_TOP; ++k) {
    const unsigned short* __restrict__ row = outw + (size_t)(b * K_TOP + k) * O_DIM;
    float v[4];
    #pragma unroll
    for (int i = 0; i < 4; ++i) v[i] = b2f(row[t + i * 256]);
    float mx = fmaxf(fmaxf(v[0], v[1]), fmaxf(v[2], v[3]));
    #pragma unroll
    for (int off = 32; off >= 1; off >>= 1) mx = fmaxf(mx, __shfl_xor(mx, off, 64));
    if ((t & 63) == 0) sred[t >> 6] = mx;
    __syncthreads();
    mx = fmaxf(fmaxf(sred[0], sred[1]), fmaxf(sred[2], sred[3]));
    __syncthreads();
    float ex[4], ps = 0.f;
    #pragma unroll
    for (int i = 0; i < 4; ++i) { ex[i] = expf(v[i] - mx); ps += ex[i]; }
    #pragma unroll
    for (int off = 32; off >= 1; off >>= 1) ps += __shfl_xor(ps, off, 64);
    if ((t & 63) == 0) sred[t >> 6] = ps;
    __syncthreads();
    ps = sred[0] + sred[1] + sred[2] + sred[3];
    __syncthreads();
    const float g = gate_bk[b * K_TOP + k];
    const float inv = 1.f / ps;
    #pragma unroll
    for (int i = 0; i < 4; ++i) yacc[i] += g * expf(ex[i] * inv);
  }
  #pragma unroll
  for (int i = 0; i < 4; ++i) y[(size_t)b * O_DIM + t + i * 256] = yacc[i];
}

// ------------------------------------------------------------------ loss ----
__global__ __launch_bounds__(256) void loss_part_kernel(
    const float* __restrict__ gates_full, const float* __restrict__ prob_ws,
    float* __restrict__ part)   // [64][2][16]
{
  const int blk = blockIdx.x, t = threadIdx.x;
  const int e = t & 15, seg = t >> 4;
  float si = 0.f, sl = 0.f;
  #pragma unroll
  for (int j = 0; j < 4; ++j) {
    const int b = blk * 64 + seg * 4 + j;
    si += gates_full[(size_t)b * E_NUM + e];
    sl += prob_ws[(size_t)b * E_NUM + e];
  }
  __shared__ float li[16][16], ll[16][16];
  li[seg][e] = si; ll[seg][e] = sl;
  __syncthreads();
  if (t < 32) {
    const int which = t >> 4, ee = t & 15;
    float s = 0.f;
    #pragma unroll
    for (int i = 0; i < 16; ++i) s += which ? ll[i][ee] : li[i][ee];
    part[(blk * 2 + which) * 16 + ee] = s;
  }
}

__global__ __launch_bounds__(64) void loss_final_kernel(
    const float* __restrict__ part, float* __restrict__ out_loss)
{
  const int t = threadIdx.x;
  __shared__ float fi[16], fl[16];
  if (t < 32) {
    const int which = t >> 4, e = t & 15;
    float s = 0.f;
    for (int i = 0; i < 64; ++i) s += part[(i * 2 + which) * 16 + e];
    if (which) fl[e] = s; else fi[e] = s;
  }
  __syncthreads();
  if (t == 0) {
    float mi = 0.f, ml = 0.f;
    #pragma unroll
    for (int e = 0; e < 16; ++e) { mi += fi[e]; ml += fl[e]; }
    mi *= (1.f / 16.f); ml *= (1.f / 16.f);
    float vi = 0.f, vl = 0.f;
    #pragma unroll
    for (int e = 0; e < 16; ++e) {
      const float di = fi[e] - mi, dl = fl[e] - ml;
      vi += di * di; vl += dl * dl;
    }
    vi *= (1.f / 15.f); vl *= (1.f / 15.f);
    out_loss[0] = (vi / (mi * mi + 1e-10f) + vl / (ml * ml + 1e-10f)) * 0.01f;
  }
}

// ---------------------------------------------------------------- launch ----
extern "C" void kernel_launch(void* const* d_in, const int* in_sizes, int n_in,
                              void* d_out, int out_size, void* d_ws, size_t ws_size,
                              hipStream_t stream)
{
  (void)in_sizes; (void)n_in; (void)out_size; (void)ws_size;
  const float* x       = (const float*)d_in[0];
  const float* noise   = (const float*)d_in[1];
  const float* w_gate  = (const float*)d_in[2];
  const float* w_noise = (const float*)d_in[3];
  const float* W1      = (const float*)d_in[4];
  const float* b1      = (const float*)d_in[5];
  const float* W2      = (const float*)d_in[6];
  const float* b2      = (const float*)d_in[7];
  float* out = (float*)d_out;

  char* wsc = (char*)d_ws;
  int*   counts     = (int*)wsc;                          // 16
  int*   ctr        = counts + 16;                        // 2 (task counters)
  int*   meta       = ctr + 2;                            // 2 (n_tasks1/2)
  int*   tasks      = meta + 2;                           // 2048 (1024 each)
  int*   pair_v     = tasks + 2048;                       // E*B
  float* gate_bk    = (float*)(pair_v + E_NUM * B_TOK);   // B*K
  float* gates_full = gate_bk + B_TOK * K_TOP;            // B*E
  float* prob_ws    = gates_full + B_TOK * E_NUM;         // B*E
  float* part       = prob_ws + B_TOK * E_NUM;            // 64*2*16
  char* big = wsc + ((((char*)(part + 64 * 2 * 16) - wsc) + 255) & ~255);
  unsigned short* x_bf = (unsigned short*)big;                         // B*D bf16 (8MB)
  unsigned short* Wt   = x_bf + (size_t)B_TOK * D_DIM;                 // 67MB shared W1t/W2t
  unsigned short* h    = Wt + (size_t)E_NUM * D_DIM * H_DIM;           // B*K*H bf16 (67MB)
  unsigned short* outw = h + (size_t)B_TOK * K_TOP * H_DIM;            // B*K*O bf16 (34MB)

  hipMemsetAsync(counts, 0, 20 * sizeof(int), stream);    // counts + ctrs + meta
  gating_kernel<<<B_TOK, 256, 0, stream>>>(x, noise, w_gate, w_noise, counts,
                                           pair_v, gate_bk, gates_full, prob_ws);
  prep_tasks_kernel<<<1, 64, 0, stream>>>(counts, tasks, meta);
  convert_x_kernel<<<(B_TOK * D_DIM / 8) / 256, 256, 0, stream>>>(x, x_bf);
  // W1 [e][D][H] -> W1t [e][H][D]
  transpose_bf16_kernel<<<dim3(H_DIM / 64, D_DIM / 64, E_NUM), 256, 0, stream>>>(
      W1, Wt, D_DIM, H_DIM);
  gemm256p_kernel<H_DIM, D_DIM, true, false><<<256, 512, 0, stream>>>(
      x_bf, Wt, b1, counts, pair_v, tasks, meta, ctr, h);
  // W2 [e][H][O] -> W2t [e][O][H]  (reuses Wt region; gemm1 is done with it)
  transpose_bf16_kernel<<<dim3(O_DIM / 64, H_DIM / 64, E_NUM), 256, 0, stream>>>(
      W2, Wt, H_DIM, O_DIM);
  gemm256p_kernel<O_DIM, H_DIM, false, true><<<256, 512, 0, stream>>>(
      h, Wt, b2, counts, pair_v, tasks + 1024, meta + 1, ctr + 1, outw);
  softmax_y_kernel<<<B_TOK, 256, 0, stream>>>(outw, gate_bk, out);
  loss_part_kernel<<<64, 256, 0, stream>>>(gates_full, prob_ws, part);
  loss_final_kernel<<<1, 64, 0, stream>>>(part, out + (size_t)B_TOK * O_DIM);
}